// Round 5
// baseline (454.922 us; speedup 1.0000x reference)
//
#include <hip/hip_runtime.h>
#include <hip/hip_cooperative_groups.h>

namespace cg = cooperative_groups;

// Focal loss (prob-space), dense [B,V] fp32 + ragged one-hot targets.
// Single cooperative kernel: streaming t=0 sum (memory-bound, 2-deep
// batched float4 loads) + per-row sparse t1-t0 correction, grid.sync,
// block 0 reduces the 1024 double partials -> fp32 scalar.
#define NT 256
#define NB 1024            // 4 blocks/CU on 256 CUs -> guaranteed co-resident
#define B_ 2048
#define V_ 32000
#define T_ 20

__device__ __forceinline__ float clip_p(float p) {
    // reference clip(p, 1e-8, 1-1e-8); fp32(1-1e-8)==1.0f and src<1 ->
    // upper clip is a no-op.
    return fmaxf(p, 1e-8f);
}

// t=0: 0.75 * p^2 * (-ln(1-p)) = C0 * p^2 * log2(1-p), C0 = -0.75*ln2
__device__ __forceinline__ float loss_t0(float pc) {
    float om = 1.0f - pc;
    return -0.51986038542f * pc * pc * __builtin_amdgcn_logf(om);
}

// t=1: 0.25 * (1-p)^2 * (-ln p) = C1 * (1-p)^2 * log2(p), C1 = -0.25*ln2
__device__ __forceinline__ float loss_t1(float pc) {
    float om = 1.0f - pc;
    return -0.17328679514f * om * om * __builtin_amdgcn_logf(pc);
}

__device__ __forceinline__ float loss4_t0(float4 v) {
    return loss_t0(clip_p(v.x)) + loss_t0(clip_p(v.y)) +
           loss_t0(clip_p(v.z)) + loss_t0(clip_p(v.w));
}

__device__ __forceinline__ double block_reduce_f64(double v) {
    #pragma unroll
    for (int off = 32; off > 0; off >>= 1) v += __shfl_down(v, off, 64);
    __shared__ double lds[NT / 64];
    int lane = threadIdx.x & 63;
    int wid  = threadIdx.x >> 6;
    if (lane == 0) lds[wid] = v;
    __syncthreads();
    double s = 0.0;
    if (threadIdx.x == 0) {
        #pragma unroll
        for (int w = 0; w < NT / 64; ++w) s += lds[w];
    }
    return s;
}

__global__ __launch_bounds__(NT, 4) void focal_all(const float* __restrict__ src,
                                                   const int* __restrict__ tgt,
                                                   double* __restrict__ part,
                                                   float* __restrict__ out) {
    double acc = 0.0;

    // --- sparse correction: block b owns rows 2b, 2b+1; threads 0..39 ---
    if (threadIdx.x < 2 * T_) {
        int row = blockIdx.x * 2 + (threadIdx.x / T_);
        int t   = threadIdx.x % T_;
        const int* trow = tgt + row * T_;
        int idx = trow[t];
        bool first = true;               // dedupe: first occurrence wins
        for (int u = 0; u < t; ++u)
            if (trow[u] == idx) first = false;
        if (first && idx >= 0 && idx < V_) {
            float pc = clip_p(src[(long)row * V_ + idx]);
            acc = (double)(loss_t1(pc) - loss_t0(pc));
        }
    }

    // --- streaming t=0 sum, 2-deep batched float4 loads ---
    const long n4 = (long)B_ * V_ / 4;   // 16,384,000; n4/stride = 62.5
    const long stride = (long)NB * NT;   // 262,144
    long i = (long)blockIdx.x * NT + threadIdx.x;
    const float4* s4 = (const float4*)src;
    for (; i + stride < n4; i += 2 * stride) {
        float4 v0 = s4[i];
        float4 v1 = s4[i + stride];
        acc += (double)loss4_t0(v0);
        acc += (double)loss4_t0(v1);
    }
    if (i < n4) acc += (double)loss4_t0(s4[i]);

    double s = block_reduce_f64(acc);
    if (threadIdx.x == 0) part[blockIdx.x] = s;

    cg::this_grid().sync();

    // --- final deterministic reduction in block 0 ---
    if (blockIdx.x == 0) {
        double a2 = 0.0;
        for (int k = threadIdx.x; k < NB; k += NT) a2 += part[k];
        double s2 = block_reduce_f64(a2);
        if (threadIdx.x == 0) out[0] = (float)s2;
    }
}

extern "C" void kernel_launch(void* const* d_in, const int* in_sizes, int n_in,
                              void* d_out, int out_size, void* d_ws, size_t ws_size,
                              hipStream_t stream) {
    const float* src = (const float*)d_in[0];
    const int*   tgt = (const int*)d_in[1];
    float*       out = (float*)d_out;
    double*      part = (double*)d_ws;   // NB doubles (8 KB)

    void* args[] = { (void*)&src, (void*)&tgt, (void*)&part, (void*)&out };
    hipLaunchCooperativeKernel((void*)focal_all, dim3(NB), dim3(NT), args, 0, stream);
}

// Round 9
// 353.808 us; speedup vs baseline: 1.2858x; 1.2858x over previous
//
#include <hip/hip_runtime.h>

// Focal loss (prob-space), dense [B,V] fp32 + ragged one-hot targets.
// R4 two-kernel structure (proven best) + 4-deep batched float4 loads for
// memory-level parallelism (R5 showed the loop is latency-bound: 688 GB/s,
// VALU 93% idle). Full occupancy: 2048 blocks = 8 blocks/CU = 32 waves/CU.
#define NT 256
#define NB 2048            // == B_: one block per row for the correction
#define B_ 2048
#define V_ 32000
#define T_ 20

__device__ __forceinline__ float clip_p(float p) {
    // reference clip(p, 1e-8, 1-1e-8); fp32(1-1e-8)==1.0f and src<1 ->
    // upper clip is a no-op.
    return fmaxf(p, 1e-8f);
}

// t=0: 0.75 * p^2 * (-ln(1-p)) = C0 * p^2 * log2(1-p), C0 = -0.75*ln2
__device__ __forceinline__ float loss_t0(float pc) {
    float om = 1.0f - pc;
    return -0.51986038542f * pc * pc * __builtin_amdgcn_logf(om);
}

// t=1: 0.25 * (1-p)^2 * (-ln p) = C1 * (1-p)^2 * log2(p), C1 = -0.25*ln2
__device__ __forceinline__ float loss_t1(float pc) {
    float om = 1.0f - pc;
    return -0.17328679514f * om * om * __builtin_amdgcn_logf(pc);
}

__device__ __forceinline__ float loss4_t0(float4 v) {
    return loss_t0(clip_p(v.x)) + loss_t0(clip_p(v.y)) +
           loss_t0(clip_p(v.z)) + loss_t0(clip_p(v.w));
}

__device__ __forceinline__ double block_reduce_f64(double v) {
    #pragma unroll
    for (int off = 32; off > 0; off >>= 1) v += __shfl_down(v, off, 64);
    __shared__ double lds[NT / 64];
    int lane = threadIdx.x & 63;
    int wid  = threadIdx.x >> 6;
    if (lane == 0) lds[wid] = v;
    __syncthreads();
    double s = 0.0;
    if (threadIdx.x == 0) {
        #pragma unroll
        for (int w = 0; w < NT / 64; ++w) s += lds[w];
    }
    return s;
}

// Fused: grid-strided t=0 sum (4-deep batched loads, block-contiguous 16KB
// chunks) + block b swaps in the t=1 term for row b's unique targets.
__global__ __launch_bounds__(NT) void focal_fused(const float* __restrict__ src,
                                                  const int* __restrict__ tgt,
                                                  double* __restrict__ part) {
    double acc = 0.0;

    // --- sparse correction: thread t (< T_) handles (row=blockIdx.x, t) ---
    if (threadIdx.x < T_) {
        int row = blockIdx.x;
        const int* trow = tgt + row * T_;
        int t   = threadIdx.x;
        int idx = trow[t];
        bool first = true;               // dedupe: first occurrence wins
        for (int u = 0; u < t; ++u)
            if (trow[u] == idx) first = false;
        if (first && idx >= 0 && idx < V_) {
            float pc = clip_p(src[(long)row * V_ + idx]);
            acc = (double)(loss_t1(pc) - loss_t0(pc));
        }
    }

    // --- streaming t=0 sum: 4 float4 loads in flight per thread ---
    const long n4 = (long)B_ * V_ / 4;   // 16,384,000 float4s
    const long SS = (long)NB * NT * 4;   // superstride: 2,097,152 (n4/SS = 7.8125)
    const float4* s4 = (const float4*)src;

    long j = (long)blockIdx.x * (4 * NT) + threadIdx.x;
    #pragma unroll 1
    for (int k = 0; k < 7; ++k, j += SS) {   // 7 full superstrides
        float4 v0 = s4[j];
        float4 v1 = s4[j + NT];
        float4 v2 = s4[j + 2 * NT];
        float4 v3 = s4[j + 3 * NT];
        float a = loss4_t0(v0) + loss4_t0(v1);
        float b = loss4_t0(v2) + loss4_t0(v3);
        acc += (double)a;
        acc += (double)b;
    }
    // tail: remaining 1,703,936 float4s, 1-deep grid-stride
    for (long i = 7 * SS + (long)blockIdx.x * NT + threadIdx.x; i < n4;
         i += (long)NB * NT)
        acc += (double)loss4_t0(s4[i]);

    double s = block_reduce_f64(acc);
    if (threadIdx.x == 0) part[blockIdx.x] = s;
}

// Final: deterministic reduction of 2048 partials -> fp32 scalar.
__global__ __launch_bounds__(NT) void focal_final(const double* __restrict__ part,
                                                  float* __restrict__ out) {
    double acc = 0.0;
    for (int i = threadIdx.x; i < NB; i += NT) acc += part[i];
    double s = block_reduce_f64(acc);
    if (threadIdx.x == 0) out[0] = (float)s;
}

extern "C" void kernel_launch(void* const* d_in, const int* in_sizes, int n_in,
                              void* d_out, int out_size, void* d_ws, size_t ws_size,
                              hipStream_t stream) {
    const float* src = (const float*)d_in[0];
    const int*   tgt = (const int*)d_in[1];
    float*       out = (float*)d_out;
    double*      part = (double*)d_ws;   // NB doubles (16 KB)

    focal_fused<<<NB, NT, 0, stream>>>(src, tgt, part);
    focal_final<<<1, NT, 0, stream>>>(part, out);
}

// Round 10
// 332.054 us; speedup vs baseline: 1.3700x; 1.0655x over previous
//
#include <hip/hip_runtime.h>

// Focal loss (prob-space), dense [B,V] fp32 + ragged one-hot targets.
// R10: attack the 3.1 TB/s read ceiling seen in R4/R9 —
//  (1) nontemporal (nt) loads: no L2/LLC allocation on the streaming miss path
//  (2) block-linear partition: each block streams ONE contiguous 125 KB chunk
//      (2048 sequential streams chip-wide instead of 32768 scattered pieces)
//  (3) 2-deep ILP, full occupancy (2048 blocks x 256 = 32 waves/CU).
#define NT 256
#define NB 2048            // == B_: one block per row for the correction
#define B_ 2048
#define V_ 32000
#define T_ 20
#define CHUNK 8000         // float4s per block: 16,384,000 / 2048

typedef float vfloat4 __attribute__((ext_vector_type(4)));

__device__ __forceinline__ vfloat4 nt_load4(const vfloat4* p) {
    return __builtin_nontemporal_load(p);   // global_load_dwordx4 ... nt
}

__device__ __forceinline__ float clip_p(float p) {
    // reference clip(p, 1e-8, 1-1e-8); fp32(1-1e-8)==1.0f and src<1 ->
    // upper clip is a no-op.
    return fmaxf(p, 1e-8f);
}

// t=0: 0.75 * p^2 * (-ln(1-p)) = C0 * p^2 * log2(1-p), C0 = -0.75*ln2
__device__ __forceinline__ float loss_t0(float pc) {
    float om = 1.0f - pc;
    return -0.51986038542f * pc * pc * __builtin_amdgcn_logf(om);
}

// t=1: 0.25 * (1-p)^2 * (-ln p) = C1 * (1-p)^2 * log2(p), C1 = -0.25*ln2
__device__ __forceinline__ float loss_t1(float pc) {
    float om = 1.0f - pc;
    return -0.17328679514f * om * om * __builtin_amdgcn_logf(pc);
}

__device__ __forceinline__ float loss4_t0(vfloat4 v) {
    return loss_t0(clip_p(v.x)) + loss_t0(clip_p(v.y)) +
           loss_t0(clip_p(v.z)) + loss_t0(clip_p(v.w));
}

__device__ __forceinline__ double block_reduce_f64(double v) {
    #pragma unroll
    for (int off = 32; off > 0; off >>= 1) v += __shfl_down(v, off, 64);
    __shared__ double lds[NT / 64];
    int lane = threadIdx.x & 63;
    int wid  = threadIdx.x >> 6;
    if (lane == 0) lds[wid] = v;
    __syncthreads();
    double s = 0.0;
    if (threadIdx.x == 0) {
        #pragma unroll
        for (int w = 0; w < NT / 64; ++w) s += lds[w];
    }
    return s;
}

// Fused: block b streams its contiguous CHUNK of src (t=0 sum, nt loads,
// 2-deep) + swaps in the t=1 term for row b's unique target indices.
__global__ __launch_bounds__(NT) void focal_fused(const float* __restrict__ src,
                                                  const int* __restrict__ tgt,
                                                  double* __restrict__ part) {
    double acc = 0.0;

    // --- sparse correction: thread t (< T_) handles (row=blockIdx.x, t) ---
    if (threadIdx.x < T_) {
        int row = blockIdx.x;
        const int* trow = tgt + row * T_;
        int t   = threadIdx.x;
        int idx = trow[t];
        bool first = true;               // dedupe: first occurrence wins
        for (int u = 0; u < t; ++u)
            if (trow[u] == idx) first = false;
        if (first && idx >= 0 && idx < V_) {
            float pc = clip_p(src[(long)row * V_ + idx]);
            acc = (double)(loss_t1(pc) - loss_t0(pc));
        }
    }

    // --- streaming t=0 sum over this block's contiguous 125 KB chunk ---
    const vfloat4* s4 = (const vfloat4*)src;
    const long base = (long)blockIdx.x * CHUNK;
    for (int k = threadIdx.x; k < CHUNK; k += 2 * NT) {
        vfloat4 v0 = nt_load4(s4 + base + k);
        bool two = (k + NT) < CHUNK;
        vfloat4 v1;
        if (two) v1 = nt_load4(s4 + base + k + NT);
        acc += (double)loss4_t0(v0);
        if (two) acc += (double)loss4_t0(v1);
    }

    double s = block_reduce_f64(acc);
    if (threadIdx.x == 0) part[blockIdx.x] = s;
}

// Final: deterministic reduction of 2048 partials -> fp32 scalar.
__global__ __launch_bounds__(NT) void focal_final(const double* __restrict__ part,
                                                  float* __restrict__ out) {
    double acc = 0.0;
    for (int i = threadIdx.x; i < NB; i += NT) acc += part[i];
    double s = block_reduce_f64(acc);
    if (threadIdx.x == 0) out[0] = (float)s;
}

extern "C" void kernel_launch(void* const* d_in, const int* in_sizes, int n_in,
                              void* d_out, int out_size, void* d_ws, size_t ws_size,
                              hipStream_t stream) {
    const float* src = (const float*)d_in[0];
    const int*   tgt = (const int*)d_in[1];
    float*       out = (float*)d_out;
    double*      part = (double*)d_ws;   // NB doubles (16 KB)

    focal_fused<<<NB, NT, 0, stream>>>(src, tgt, part);
    focal_final<<<1, NT, 0, stream>>>(part, out);
}